// Round 1
// baseline (464.597 us; speedup 1.0000x reference)
//
#include <hip/hip_runtime.h>
#include <hip/hip_bf16.h>
#include <hip/hip_fp16.h>
#include <math.h>

// Problem constants
#define DD   1024
#define EE   8
#define HH   512
#define NTOK 16384        // B*T
#define NG   16           // (expert, slot) groups
#define MAXMT 24          // max 128-row tiles per group (n_g ~ 2048 +- ~200)

typedef __attribute__((ext_vector_type(8))) short short8;   // 8 bf16
typedef __attribute__((ext_vector_type(4))) float floatx4;  // MFMA C/D frag

__device__ __forceinline__ ushort f2bfu(float f) {
    __hip_bfloat16 h = __float2bfloat16(f);   // RNE
    return *reinterpret_cast<ushort*>(&h);
}
__device__ __forceinline__ float bfu2f(ushort u) {
    union { unsigned u; float f; } cv; cv.u = ((unsigned)u) << 16; return cv.f;
}

// async global->LDS, 16B per lane. LDS dest = wave-uniform base + lane*16.
__device__ __forceinline__ void glds16(const void* g, void* l) {
    __builtin_amdgcn_global_load_lds(
        (const __attribute__((address_space(1))) unsigned int*)g,
        (__attribute__((address_space(3))) unsigned int*)l, 16, 0, 0);
}

// ---------------------------------------------------------------------------
// Kernel 1: per-expert transpose + cvt: src [E][R][C] fp32 -> dst [E][C][R] bf16
// First launch also zeroes the 256-int counter region (folds old zero_k:
// one fewer 1-block stream-serial bubble).
// ---------------------------------------------------------------------------
__global__ __launch_bounds__(256) void trans_k(const float* __restrict__ src, ushort* __restrict__ dst,
                                               const int R, const int C, int* __restrict__ cnt) {
    if (cnt && blockIdx.x == 0 && blockIdx.y == 0 && blockIdx.z == 0 && threadIdx.x < 256)
        cnt[threadIdx.x] = 0;
    const int e = blockIdx.z, r0 = blockIdx.y * 64, c0 = blockIdx.x * 64;
    __shared__ float t[64][65];
    const int tid = threadIdx.x;
    const int cseg = (tid & 15) * 4, rr = tid >> 4;
#pragma unroll
    for (int j = 0; j < 4; ++j) {
        const int r = rr + j * 16;
        const float4 v = *(const float4*)(src + ((size_t)e * R + r0 + r) * C + c0 + cseg);
        t[r][cseg] = v.x; t[r][cseg+1] = v.y; t[r][cseg+2] = v.z; t[r][cseg+3] = v.w;
    }
    __syncthreads();
    const int rseg = (tid & 15) * 4;
#pragma unroll
    for (int j = 0; j < 4; ++j) {
        const int crow = (tid >> 4) + j * 16;
        ushort o[4];
#pragma unroll
        for (int q = 0; q < 4; ++q) o[q] = f2bfu(t[rseg + q][crow]);
        *(uint2*)(dst + ((size_t)e * C + c0 + crow) * R + r0 + rseg) = *(uint2*)o;
    }
}

// ---------------------------------------------------------------------------
// Kernel 2: router (fp32 math) + x -> bf16 conversion fused.
// 2 tokens/wave, lane owns 4 consecutive d:
//   - float4 x loads (16B/lane), uint2 bf16x4 stores (8B/lane)  [G13]
//   - each 128B weight read is shared across both tokens -> Wr/Wn L2 traffic
//     64KB -> 16KB per token (4x). 32 live accumulators (64 regressed before).
// entry = tok | gate_f16 << 16, appended to group g = expert*2 + slot.
// ---------------------------------------------------------------------------
#define ROUTER_TAIL(AR, AN, T) do {                                           \
    const int t_ = (T);                                                       \
    float noisy[EE];                                                          \
    _Pragma("unroll")                                                         \
    for (int e = 0; e < EE; ++e) {                                            \
        const float lg = AR[e] + br[e];                                       \
        const float nl = AN[e] + bn[e];                                       \
        const float sp = fmaxf(nl, 0.f) + log1pf(expf(-fabsf(nl)));           \
        noisy[e] = lg + noise[(size_t)t_ * EE + e] * sp;                      \
    }                                                                         \
    int i0 = 0;                                                               \
    _Pragma("unroll")                                                         \
    for (int e = 1; e < EE; ++e) if (noisy[e] > noisy[i0]) i0 = e;            \
    int i1 = (i0 == 0) ? 1 : 0;                                               \
    _Pragma("unroll")                                                         \
    for (int e = 0; e < EE; ++e) if (e != i0 && noisy[e] > noisy[i1]) i1 = e; \
    const float ex = expf(noisy[i1] - noisy[i0]);                             \
    const float g0 = 1.f / (1.f + ex);                                        \
    const float g1 = ex / (1.f + ex);                                         \
    __half h0 = __float2half_rn(g0), h1 = __float2half_rn(g1);                \
    const unsigned u0 = (unsigned)t_ | ((unsigned)*reinterpret_cast<ushort*>(&h0) << 16); \
    const unsigned u1 = (unsigned)t_ | ((unsigned)*reinterpret_cast<ushort*>(&h1) << 16); \
    const int ga = i0 * 2 + 0, gb = i1 * 2 + 1;                               \
    int p0 = atomicAdd(&cnt[ga * 16], 1);                                     \
    entries[ga * NTOK + p0] = u0;                                             \
    int p1 = atomicAdd(&cnt[gb * 16], 1);                                     \
    entries[gb * NTOK + p1] = u1;                                             \
} while (0)

__global__ __launch_bounds__(256) void router_k(
    const float* __restrict__ x, const float* __restrict__ Wr, const float* __restrict__ br,
    const float* __restrict__ Wn, const float* __restrict__ bn, const float* __restrict__ noise,
    int* __restrict__ cnt, unsigned* __restrict__ entries, ushort* __restrict__ xb)
{
    const int wave = threadIdx.x >> 6;
    const int lane = threadIdx.x & 63;
    const int t0 = blockIdx.x * 8 + wave * 2;

    float a0r[EE], a0n[EE], a1r[EE], a1n[EE];
#pragma unroll
    for (int e = 0; e < EE; ++e) { a0r[e] = 0.f; a0n[e] = 0.f; a1r[e] = 0.f; a1n[e] = 0.f; }

    const float* xr0 = x + (size_t)t0 * DD;
    const float* xr1 = xr0 + DD;
    ushort* xb0 = xb + (size_t)t0 * DD;
    ushort* xb1 = xb0 + DD;

#pragma unroll
    for (int it = 0; it < DD / 256; ++it) {
        const int d = it * 256 + lane * 4;
        const float4 xv0 = *(const float4*)(xr0 + d);
        const float4 xv1 = *(const float4*)(xr1 + d);
        ushort o0[4] = { f2bfu(xv0.x), f2bfu(xv0.y), f2bfu(xv0.z), f2bfu(xv0.w) };
        ushort o1[4] = { f2bfu(xv1.x), f2bfu(xv1.y), f2bfu(xv1.z), f2bfu(xv1.w) };
        *(uint2*)(xb0 + d) = *(const uint2*)o0;
        *(uint2*)(xb1 + d) = *(const uint2*)o1;
        const float xs0[4] = { xv0.x, xv0.y, xv0.z, xv0.w };
        const float xs1[4] = { xv1.x, xv1.y, xv1.z, xv1.w };
#pragma unroll
        for (int q = 0; q < 4; ++q) {
            float wr[8], wn[8];
            *(float4*)&wr[0] = *(const float4*)(Wr + (size_t)(d + q) * EE);
            *(float4*)&wr[4] = *(const float4*)(Wr + (size_t)(d + q) * EE + 4);
            *(float4*)&wn[0] = *(const float4*)(Wn + (size_t)(d + q) * EE);
            *(float4*)&wn[4] = *(const float4*)(Wn + (size_t)(d + q) * EE + 4);
#pragma unroll
            for (int e = 0; e < EE; ++e) {
                a0r[e] = fmaf(xs0[q], wr[e], a0r[e]);
                a0n[e] = fmaf(xs0[q], wn[e], a0n[e]);
                a1r[e] = fmaf(xs1[q], wr[e], a1r[e]);
                a1n[e] = fmaf(xs1[q], wn[e], a1n[e]);
            }
        }
    }
#pragma unroll
    for (int off = 32; off > 0; off >>= 1) {
#pragma unroll
        for (int e = 0; e < EE; ++e) {
            a0r[e] += __shfl_xor(a0r[e], off);
            a0n[e] += __shfl_xor(a0n[e], off);
            a1r[e] += __shfl_xor(a1r[e], off);
            a1n[e] += __shfl_xor(a1n[e], off);
        }
    }
    if (lane == 0) {
        ROUTER_TAIL(a0r, a0n, t0);
        ROUTER_TAIL(a1r, a1n, t0 + 1);
    }
}

// ---------------------------------------------------------------------------
// Grouped GEMM: 128x128x64 tile, 4 waves (2x2), XOR-swizzled LDS (0 bank
// conflicts, verified r6). Flat 1-D grid with the N-slice in the LOW bits:
// if block->XCD assignment round-robins (bx % 8), all blocks reading a given
// weight N-slice land on one XCD -> slice fetched once per chip, and
// consecutive bx share the A-tile (L2 hits both ways).
// offsets_k folded away: each block computes the exclusive prefix over the
// 16 L2-hot counters itself (<=15 uniform loads, once per block).
// ---------------------------------------------------------------------------

// Kernel 4: down: hid[off+row][n] = gelu(x_gathered @ WdT^T + bd)
// grid: bx = ((g*MAXMT + tm)*4 + n0q), n0 = n0q*128
__global__ __launch_bounds__(256) void down_k(
    const ushort* __restrict__ xb, const ushort* __restrict__ WdT, const float* __restrict__ bd,
    const int* __restrict__ cnt, const unsigned* __restrict__ entries, ushort* __restrict__ hid)
{
    const int bx = blockIdx.x;
    const int n0 = (bx & 3) * 128;
    const int tmg = bx >> 2;
    const int tm = tmg % MAXMT;
    const int g = tmg / MAXMT, e = g >> 1;
    const int n_g = cnt[g * 16];
    if (tm * 128 >= n_g) return;

    int og = 0;
    for (int gg = 0; gg < g; ++gg) og += cnt[gg * 16];   // exclusive prefix

    __shared__ __align__(16) ushort As[128 * 64];
    __shared__ __align__(16) ushort Bs[128 * 64];
    __shared__ unsigned ecache[128];

    const int tid = threadIdx.x, lane = tid & 63, w = tid >> 6;
    const int wm = w >> 1, wn = w & 1;
    const int fr = lane & 15, fq = lane >> 4;

    if (tid < 128) {
        const int ridx = min(tm * 128 + tid, n_g - 1);
        ecache[tid] = entries[g * NTOK + ridx];
    }
    __syncthreads();

    const int lr = lane >> 3, seg = lane & 7;
    const int slog = seg ^ lr;                 // row&7 == lr for all j
    const ushort* gA[4]; const ushort* gB[4];
    char* lA[4]; char* lB[4];
    const ushort* WTe = WdT + (size_t)e * HH * DD;
#pragma unroll
    for (int j = 0; j < 4; ++j) {
        const int row = w * 32 + j * 8 + lr;
        const int tok = (int)(ecache[row] & 0xFFFFu);
        gA[j] = xb + (size_t)tok * DD + slog * 8;
        gB[j] = WTe + (size_t)(n0 + row) * DD + slog * 8;
        lA[j] = (char*)As + (size_t)(w * 256 + j * 64) * 16;
        lB[j] = (char*)Bs + (size_t)(w * 256 + j * 64) * 16;
    }

    floatx4 acc[4][4];
#pragma unroll
    for (int i = 0; i < 4; ++i)
#pragma unroll
        for (int j = 0; j < 4; ++j) acc[i][j] = (floatx4){0.f, 0.f, 0.f, 0.f};

    const int axr = wm * 64 + fr;
    const int bxr = wn * 64 + fr;

    for (int k0 = 0; k0 < DD; k0 += 64) {
        __syncthreads();
#pragma unroll
        for (int j = 0; j < 4; ++j) { glds16(gA[j] + k0, lA[j]); glds16(gB[j] + k0, lB[j]); }
        __syncthreads();
#pragma unroll
        for (int kh = 0; kh < 2; ++kh) {
            short8 a[4], b[4];
#pragma unroll
            for (int mt = 0; mt < 4; ++mt) {
                const int r = axr + mt * 16;
                a[mt] = *(const short8*)&As[r * 64 + ((kh * 4 + fq) ^ (r & 7)) * 8];
            }
#pragma unroll
            for (int nt = 0; nt < 4; ++nt) {
                const int r = bxr + nt * 16;
                b[nt] = *(const short8*)&Bs[r * 64 + ((kh * 4 + fq) ^ (r & 7)) * 8];
            }
#pragma unroll
            for (int mt = 0; mt < 4; ++mt)
#pragma unroll
                for (int nt = 0; nt < 4; ++nt)
                    acc[mt][nt] = __builtin_amdgcn_mfma_f32_16x16x32_bf16(a[mt], b[nt], acc[mt][nt], 0, 0, 0);
        }
    }

    const int hbase = og + tm * 128;
#pragma unroll
    for (int nt = 0; nt < 4; ++nt) {
        const int n = n0 + wn * 64 + nt * 16 + fr;
        const float bias = bd[e * HH + n];
#pragma unroll
        for (int mt = 0; mt < 4; ++mt)
#pragma unroll
            for (int i = 0; i < 4; ++i) {
                const int rl = wm * 64 + mt * 16 + fq * 4 + i;
                if (tm * 128 + rl < n_g) {
                    const float v = acc[mt][nt][i] + bias;
                    const float ge = 0.5f * v * (1.f + erff(v * 0.7071067811865475f));
                    hid[(size_t)(hbase + rl) * HH + n] = f2bfu(ge);
                }
            }
    }
}

// Kernel 5: up, SINGLE pass over all 16 groups:
//   slots[tok*2+slot][n] = (hid @ WuT^T + bu) * gate   (bf16, write-only)
// Every slot row is written exactly once -> no atomics, no RMW, no ordering.
// grid: bx = ((g*MAXMT + tm)*8 + n0q), n0 = n0q*128
__global__ __launch_bounds__(256) void up_k(
    const ushort* __restrict__ hid, const ushort* __restrict__ WuT, const float* __restrict__ bu,
    const int* __restrict__ cnt, const unsigned* __restrict__ entries, ushort* __restrict__ slots)
{
    const int bx = blockIdx.x;
    const int n0 = (bx & 7) * 128;
    const int tmg = bx >> 3;
    const int tm = tmg % MAXMT;
    const int g = tmg / MAXMT, e = g >> 1, slot = g & 1;
    const int n_g = cnt[g * 16];
    if (tm * 128 >= n_g) return;

    int hbase = 0;
    for (int gg = 0; gg < g; ++gg) hbase += cnt[gg * 16];  // exclusive prefix

    __shared__ __align__(16) ushort As[128 * 64];
    __shared__ __align__(16) ushort Bs[128 * 64];
    __shared__ unsigned ecache[128];

    const int tid = threadIdx.x, lane = tid & 63, w = tid >> 6;
    const int wm = w >> 1, wn = w & 1;
    const int fr = lane & 15, fq = lane >> 4;

    if (tid < 128) {
        const int ridx = min(tm * 128 + tid, n_g - 1);
        ecache[tid] = entries[g * NTOK + ridx];
    }
    __syncthreads();

    const int lr = lane >> 3, seg = lane & 7;
    const int slog = seg ^ lr;
    const ushort* gA[4]; const ushort* gB[4];
    char* lA[4]; char* lB[4];
    const ushort* WTe = WuT + (size_t)e * DD * HH;
#pragma unroll
    for (int j = 0; j < 4; ++j) {
        const int row = w * 32 + j * 8 + lr;
        const int ar = min(tm * 128 + row, n_g - 1);
        gA[j] = hid + (size_t)(hbase + ar) * HH + slog * 8;
        gB[j] = WTe + (size_t)(n0 + row) * HH + slog * 8;
        lA[j] = (char*)As + (size_t)(w * 256 + j * 64) * 16;
        lB[j] = (char*)Bs + (size_t)(w * 256 + j * 64) * 16;
    }

    floatx4 acc[4][4];
#pragma unroll
    for (int i = 0; i < 4; ++i)
#pragma unroll
        for (int j = 0; j < 4; ++j) acc[i][j] = (floatx4){0.f, 0.f, 0.f, 0.f};

    const int axr = wm * 64 + fr;
    const int bxr = wn * 64 + fr;

    for (int k0 = 0; k0 < HH; k0 += 64) {
        __syncthreads();
#pragma unroll
        for (int j = 0; j < 4; ++j) { glds16(gA[j] + k0, lA[j]); glds16(gB[j] + k0, lB[j]); }
        __syncthreads();
#pragma unroll
        for (int kh = 0; kh < 2; ++kh) {
            short8 a[4], b[4];
#pragma unroll
            for (int mt = 0; mt < 4; ++mt) {
                const int r = axr + mt * 16;
                a[mt] = *(const short8*)&As[r * 64 + ((kh * 4 + fq) ^ (r & 7)) * 8];
            }
#pragma unroll
            for (int nt = 0; nt < 4; ++nt) {
                const int r = bxr + nt * 16;
                b[nt] = *(const short8*)&Bs[r * 64 + ((kh * 4 + fq) ^ (r & 7)) * 8];
            }
#pragma unroll
            for (int mt = 0; mt < 4; ++mt)
#pragma unroll
                for (int nt = 0; nt < 4; ++nt)
                    acc[mt][nt] = __builtin_amdgcn_mfma_f32_16x16x32_bf16(a[mt], b[nt], acc[mt][nt], 0, 0, 0);
        }
    }

#pragma unroll
    for (int nt = 0; nt < 4; ++nt) {
        const int n = n0 + wn * 64 + nt * 16 + fr;
        const float bias = bu[e * DD + n];
#pragma unroll
        for (int mt = 0; mt < 4; ++mt)
#pragma unroll
            for (int i = 0; i < 4; ++i) {
                const int rl = wm * 64 + mt * 16 + fq * 4 + i;
                if (tm * 128 + rl < n_g) {
                    const unsigned en = ecache[rl];
                    const int tok = (int)(en & 0xFFFFu);
                    ushort hb = (ushort)(en >> 16);
                    const float gate = __half2float(*reinterpret_cast<__half*>(&hb));
                    const float v = (acc[mt][nt][i] + bias) * gate;
                    slots[((size_t)tok * 2 + slot) * DD + n] = f2bfu(v);
                }
            }
    }
}

// Kernel 6: out[t][d] = slots[2t][d] + slots[2t+1][d]  (fp32 out, 8 elems/thread)
__global__ __launch_bounds__(256) void combine_k(
    const ushort* __restrict__ slots, float* __restrict__ out)
{
    const size_t flat = ((size_t)blockIdx.x * 256 + threadIdx.x) * 8;
    const size_t t = flat >> 10;         // / DD
    const size_t d = flat & (DD - 1);
    union { uint4 v; ushort h[8]; } a, b;
    a.v = *(const uint4*)(slots + ((t * 2 + 0) << 10) + d);
    b.v = *(const uint4*)(slots + ((t * 2 + 1) << 10) + d);
    float o[8];
#pragma unroll
    for (int j = 0; j < 8; ++j) o[j] = bfu2f(a.h[j]) + bfu2f(b.h[j]);
    *(float4*)(out + flat) = *(const float4*)&o[0];
    *(float4*)(out + flat + 4) = *(const float4*)&o[4];
}

// ---------------------------------------------------------------------------
// Workspace layout (bytes), total ~145 MB:
//   0         cnt    : int[16] @ 64B stride (256-int region zeroed by trans_k)
//   1024      (unused; old off slot)
//   2048      entries: u32[16][16384]            (1 MB)
//   1050624   xb     : bf16 [16384][1024]        (32 MB)
//   34605056  WdT    : bf16 [8][512 h][1024 d]   (8 MB)
//   42993664  WuT    : bf16 [8][1024 d][512 h]   (8 MB)
//   51382272  hid    : bf16 [32768][512]         (32 MB)
//   84936704  slots  : bf16 [32768][1024]        (64 MB)
// ---------------------------------------------------------------------------
extern "C" void kernel_launch(void* const* d_in, const int* in_sizes, int n_in,
                              void* d_out, int out_size, void* d_ws, size_t ws_size,
                              hipStream_t stream)
{
    const float* x     = (const float*)d_in[0];
    const float* Wr    = (const float*)d_in[1];
    const float* br    = (const float*)d_in[2];
    const float* Wn    = (const float*)d_in[3];
    const float* bn    = (const float*)d_in[4];
    const float* Wd    = (const float*)d_in[5];
    const float* bd    = (const float*)d_in[6];
    const float* Wu    = (const float*)d_in[7];
    const float* bu    = (const float*)d_in[8];
    const float* noise = (const float*)d_in[9];

    char* ws = (char*)d_ws;
    int*      cnt     = (int*)(ws + 0);
    unsigned* entries = (unsigned*)(ws + 2048);
    ushort*   xb      = (ushort*)(ws + 1050624);
    ushort*   WdT     = (ushort*)(ws + 34605056);
    ushort*   WuT     = (ushort*)(ws + 42993664);
    ushort*   hid     = (ushort*)(ws + 51382272);
    ushort*   slots   = (ushort*)(ws + 84936704);

    trans_k<<<dim3(HH / 64, DD / 64, EE), 256, 0, stream>>>(Wd, WdT, DD, HH, cnt);      // [d][h]->[h][d] + zero cnt
    trans_k<<<dim3(DD / 64, HH / 64, EE), 256, 0, stream>>>(Wu, WuT, HH, DD, nullptr);  // [h][d]->[d][h]
    router_k<<<NTOK / 8, 256, 0, stream>>>(x, Wr, br, Wn, bn, noise, cnt, entries, xb);
    down_k<<<NG * MAXMT * 4, 256, 0, stream>>>(xb, WdT, bd, cnt, entries, hid);
    up_k<<<NG * MAXMT * 8, 256, 0, stream>>>(hid, WuT, bu, cnt, entries, slots);
    combine_k<<<(NTOK * DD) / (256 * 8), 256, 0, stream>>>(slots, (float*)d_out);
}

// Round 2
// 427.486 us; speedup vs baseline: 1.0868x; 1.0868x over previous
//
#include <hip/hip_runtime.h>
#include <hip/hip_bf16.h>
#include <hip/hip_fp16.h>
#include <math.h>

// Problem constants
#define DD   1024
#define EE   8
#define HH   512
#define NTOK 16384        // B*T
#define NG   16           // (expert, slot) groups
#define MAXMT 24          // max 128-row tiles per group (n_g ~ 2048 +- ~200)

typedef __attribute__((ext_vector_type(8))) short short8;   // 8 bf16
typedef __attribute__((ext_vector_type(4))) float floatx4;  // MFMA C/D frag

__device__ __forceinline__ ushort f2bfu(float f) {
    __hip_bfloat16 h = __float2bfloat16(f);   // RNE
    return *reinterpret_cast<ushort*>(&h);
}
__device__ __forceinline__ float bfu2f(ushort u) {
    union { unsigned u; float f; } cv; cv.u = ((unsigned)u) << 16; return cv.f;
}

// async global->LDS, 16B per lane. LDS dest = wave-uniform base + lane*16.
__device__ __forceinline__ void glds16(const void* g, void* l) {
    __builtin_amdgcn_global_load_lds(
        (const __attribute__((address_space(1))) unsigned int*)g,
        (__attribute__((address_space(3))) unsigned int*)l, 16, 0, 0);
}

// ---------------------------------------------------------------------------
// Kernel 1: per-expert transpose + cvt: src [E][R][C] fp32 -> dst [E][C][R] bf16
// First launch also zeroes the 256-int counter region.
// ---------------------------------------------------------------------------
__global__ __launch_bounds__(256) void trans_k(const float* __restrict__ src, ushort* __restrict__ dst,
                                               const int R, const int C, int* __restrict__ cnt) {
    if (cnt && blockIdx.x == 0 && blockIdx.y == 0 && blockIdx.z == 0 && threadIdx.x < 256)
        cnt[threadIdx.x] = 0;
    const int e = blockIdx.z, r0 = blockIdx.y * 64, c0 = blockIdx.x * 64;
    __shared__ float t[64][65];
    const int tid = threadIdx.x;
    const int cseg = (tid & 15) * 4, rr = tid >> 4;
#pragma unroll
    for (int j = 0; j < 4; ++j) {
        const int r = rr + j * 16;
        const float4 v = *(const float4*)(src + ((size_t)e * R + r0 + r) * C + c0 + cseg);
        t[r][cseg] = v.x; t[r][cseg+1] = v.y; t[r][cseg+2] = v.z; t[r][cseg+3] = v.w;
    }
    __syncthreads();
    const int rseg = (tid & 15) * 4;
#pragma unroll
    for (int j = 0; j < 4; ++j) {
        const int crow = (tid >> 4) + j * 16;
        ushort o[4];
#pragma unroll
        for (int q = 0; q < 4; ++q) o[q] = f2bfu(t[rseg + q][crow]);
        *(uint2*)(dst + ((size_t)e * C + c0 + crow) * R + r0 + rseg) = *(uint2*)o;
    }
}

// ---------------------------------------------------------------------------
// Kernel 2: router (fp32 math) + x -> bf16 conversion fused.
// v3: weights staged in LDS. Previous version gathered Wr/Wn from L2 with
// lanes striding 128B -> 8x cacheline amplification -> 4.3 GB of L2 traffic
// (= the measured 117 us). Now: one 64 KB coalesced stage per block, then
// bank-minimal LDS reads.
//   LDS layout WT[d][20] fp32 (80B row, pad 4): lane reads 4x b128 at word
//   20*lane + 4c -> chunk bank-group (5*lane+c)%8, 5 coprime 8 -> all 8
//   groups covered, 8 words/bank = structural minimum (conflict-free).
//   row k=0..7: Wr[d][e], k=8..15: Wn[d][e].
// d-ownership: d = s*64 + lane (stride-64) -> scalar x loads / xb stores
// stay fully coalesced.
// 512 threads = 8 waves x 2 tokens; 80 KB LDS -> 2 blocks/CU = 16 waves/CU.
// entry = tok | gate_f16 << 16, appended to group g = expert*2 + slot.
// ---------------------------------------------------------------------------
#define ROUTER_TAIL(AR, AN, T) do {                                           \
    const int t_ = (T);                                                       \
    float noisy[EE];                                                          \
    _Pragma("unroll")                                                         \
    for (int e = 0; e < EE; ++e) {                                            \
        const float lg = AR[e] + br[e];                                       \
        const float nl = AN[e] + bn[e];                                       \
        const float sp = fmaxf(nl, 0.f) + log1pf(expf(-fabsf(nl)));           \
        noisy[e] = lg + noise[(size_t)t_ * EE + e] * sp;                      \
    }                                                                         \
    int i0 = 0;                                                               \
    _Pragma("unroll")                                                         \
    for (int e = 1; e < EE; ++e) if (noisy[e] > noisy[i0]) i0 = e;            \
    int i1 = (i0 == 0) ? 1 : 0;                                               \
    _Pragma("unroll")                                                         \
    for (int e = 0; e < EE; ++e) if (e != i0 && noisy[e] > noisy[i1]) i1 = e; \
    const float ex = expf(noisy[i1] - noisy[i0]);                             \
    const float g0 = 1.f / (1.f + ex);                                        \
    const float g1 = ex / (1.f + ex);                                         \
    __half h0 = __float2half_rn(g0), h1 = __float2half_rn(g1);                \
    const unsigned u0 = (unsigned)t_ | ((unsigned)*reinterpret_cast<ushort*>(&h0) << 16); \
    const unsigned u1 = (unsigned)t_ | ((unsigned)*reinterpret_cast<ushort*>(&h1) << 16); \
    const int ga = i0 * 2 + 0, gb = i1 * 2 + 1;                               \
    int p0 = atomicAdd(&cnt[ga * 16], 1);                                     \
    entries[ga * NTOK + p0] = u0;                                             \
    int p1 = atomicAdd(&cnt[gb * 16], 1);                                     \
    entries[gb * NTOK + p1] = u1;                                             \
} while (0)

__global__ __launch_bounds__(512) void router_k(
    const float* __restrict__ x, const float* __restrict__ Wr, const float* __restrict__ br,
    const float* __restrict__ Wn, const float* __restrict__ bn, const float* __restrict__ noise,
    int* __restrict__ cnt, unsigned* __restrict__ entries, ushort* __restrict__ xb)
{
    __shared__ __align__(16) float WT[DD * 20];   // 80 KB

    const int tid = threadIdx.x;
    // ---- stage Wr/Wn -> WT[d][20] (coalesced global float4 reads) ----
    {
        const int d0 = tid * 2;
#pragma unroll
        for (int r = 0; r < 2; ++r) {
            const int d = d0 + r;
            float4 a = *(const float4*)(Wr + (size_t)d * EE);
            float4 b = *(const float4*)(Wr + (size_t)d * EE + 4);
            float4 c = *(const float4*)(Wn + (size_t)d * EE);
            float4 e4 = *(const float4*)(Wn + (size_t)d * EE + 4);
            float* row = &WT[d * 20];
            *(float4*)(row + 0)  = a;
            *(float4*)(row + 4)  = b;
            *(float4*)(row + 8)  = c;
            *(float4*)(row + 12) = e4;
        }
    }
    __syncthreads();

    const int wave = tid >> 6;
    const int lane = tid & 63;
    const int t0 = blockIdx.x * 16 + wave * 2;

    float a0r[EE], a0n[EE], a1r[EE], a1n[EE];
#pragma unroll
    for (int e = 0; e < EE; ++e) { a0r[e] = 0.f; a0n[e] = 0.f; a1r[e] = 0.f; a1n[e] = 0.f; }

    const float* xr0 = x + (size_t)t0 * DD;
    const float* xr1 = xr0 + DD;
    ushort* xb0 = xb + (size_t)t0 * DD;
    ushort* xb1 = xb0 + DD;

#pragma unroll 4
    for (int s = 0; s < DD / 64; ++s) {
        const int d = s * 64 + lane;
        const float x0 = xr0[d];
        const float x1 = xr1[d];
        xb0[d] = f2bfu(x0);
        xb1[d] = f2bfu(x1);
        const float* row = &WT[d * 20];
        const float4 w0 = *(const float4*)(row + 0);    // Wr e0-3
        const float4 w1 = *(const float4*)(row + 4);    // Wr e4-7
        const float4 w2 = *(const float4*)(row + 8);    // Wn e0-3
        const float4 w3 = *(const float4*)(row + 12);   // Wn e4-7
        const float wr[8] = { w0.x, w0.y, w0.z, w0.w, w1.x, w1.y, w1.z, w1.w };
        const float wn[8] = { w2.x, w2.y, w2.z, w2.w, w3.x, w3.y, w3.z, w3.w };
#pragma unroll
        for (int e = 0; e < EE; ++e) {
            a0r[e] = fmaf(x0, wr[e], a0r[e]);
            a0n[e] = fmaf(x0, wn[e], a0n[e]);
            a1r[e] = fmaf(x1, wr[e], a1r[e]);
            a1n[e] = fmaf(x1, wn[e], a1n[e]);
        }
    }
#pragma unroll
    for (int off = 32; off > 0; off >>= 1) {
#pragma unroll
        for (int e = 0; e < EE; ++e) {
            a0r[e] += __shfl_xor(a0r[e], off);
            a0n[e] += __shfl_xor(a0n[e], off);
            a1r[e] += __shfl_xor(a1r[e], off);
            a1n[e] += __shfl_xor(a1n[e], off);
        }
    }
    if (lane == 0) {
        ROUTER_TAIL(a0r, a0n, t0);
        ROUTER_TAIL(a1r, a1n, t0 + 1);
    }
}

// ---------------------------------------------------------------------------
// Grouped GEMM: 128x128x64 tile, 4 waves (2x2), XOR-swizzled LDS (0 bank
// conflicts, verified r6). Flat 1-D grid with the N-slice in the LOW bits:
// if block->XCD assignment round-robins (bx % 8), all blocks reading a given
// weight N-slice land on one XCD -> slice fetched once per chip, and
// consecutive bx share the A-tile (L2 hits both ways).
// offsets_k folded away: each block computes the exclusive prefix over the
// 16 L2-hot counters itself (<=15 uniform loads, once per block).
// ---------------------------------------------------------------------------

// Kernel 4: down: hid[off+row][n] = gelu(x_gathered @ WdT^T + bd)
// grid: bx = ((g*MAXMT + tm)*4 + n0q), n0 = n0q*128
__global__ __launch_bounds__(256) void down_k(
    const ushort* __restrict__ xb, const ushort* __restrict__ WdT, const float* __restrict__ bd,
    const int* __restrict__ cnt, const unsigned* __restrict__ entries, ushort* __restrict__ hid)
{
    const int bx = blockIdx.x;
    const int n0 = (bx & 3) * 128;
    const int tmg = bx >> 2;
    const int tm = tmg % MAXMT;
    const int g = tmg / MAXMT, e = g >> 1;
    const int n_g = cnt[g * 16];
    if (tm * 128 >= n_g) return;

    int og = 0;
    for (int gg = 0; gg < g; ++gg) og += cnt[gg * 16];   // exclusive prefix

    __shared__ __align__(16) ushort As[128 * 64];
    __shared__ __align__(16) ushort Bs[128 * 64];
    __shared__ unsigned ecache[128];

    const int tid = threadIdx.x, lane = tid & 63, w = tid >> 6;
    const int wm = w >> 1, wn = w & 1;
    const int fr = lane & 15, fq = lane >> 4;

    if (tid < 128) {
        const int ridx = min(tm * 128 + tid, n_g - 1);
        ecache[tid] = entries[g * NTOK + ridx];
    }
    __syncthreads();

    const int lr = lane >> 3, seg = lane & 7;
    const int slog = seg ^ lr;                 // row&7 == lr for all j
    const ushort* gA[4]; const ushort* gB[4];
    char* lA[4]; char* lB[4];
    const ushort* WTe = WdT + (size_t)e * HH * DD;
#pragma unroll
    for (int j = 0; j < 4; ++j) {
        const int row = w * 32 + j * 8 + lr;
        const int tok = (int)(ecache[row] & 0xFFFFu);
        gA[j] = xb + (size_t)tok * DD + slog * 8;
        gB[j] = WTe + (size_t)(n0 + row) * DD + slog * 8;
        lA[j] = (char*)As + (size_t)(w * 256 + j * 64) * 16;
        lB[j] = (char*)Bs + (size_t)(w * 256 + j * 64) * 16;
    }

    floatx4 acc[4][4];
#pragma unroll
    for (int i = 0; i < 4; ++i)
#pragma unroll
        for (int j = 0; j < 4; ++j) acc[i][j] = (floatx4){0.f, 0.f, 0.f, 0.f};

    const int axr = wm * 64 + fr;
    const int bxr = wn * 64 + fr;

    for (int k0 = 0; k0 < DD; k0 += 64) {
        __syncthreads();
#pragma unroll
        for (int j = 0; j < 4; ++j) { glds16(gA[j] + k0, lA[j]); glds16(gB[j] + k0, lB[j]); }
        __syncthreads();
#pragma unroll
        for (int kh = 0; kh < 2; ++kh) {
            short8 a[4], b[4];
#pragma unroll
            for (int mt = 0; mt < 4; ++mt) {
                const int r = axr + mt * 16;
                a[mt] = *(const short8*)&As[r * 64 + ((kh * 4 + fq) ^ (r & 7)) * 8];
            }
#pragma unroll
            for (int nt = 0; nt < 4; ++nt) {
                const int r = bxr + nt * 16;
                b[nt] = *(const short8*)&Bs[r * 64 + ((kh * 4 + fq) ^ (r & 7)) * 8];
            }
#pragma unroll
            for (int mt = 0; mt < 4; ++mt)
#pragma unroll
                for (int nt = 0; nt < 4; ++nt)
                    acc[mt][nt] = __builtin_amdgcn_mfma_f32_16x16x32_bf16(a[mt], b[nt], acc[mt][nt], 0, 0, 0);
        }
    }

    const int hbase = og + tm * 128;
#pragma unroll
    for (int nt = 0; nt < 4; ++nt) {
        const int n = n0 + wn * 64 + nt * 16 + fr;
        const float bias = bd[e * HH + n];
#pragma unroll
        for (int mt = 0; mt < 4; ++mt)
#pragma unroll
            for (int i = 0; i < 4; ++i) {
                const int rl = wm * 64 + mt * 16 + fq * 4 + i;
                if (tm * 128 + rl < n_g) {
                    const float v = acc[mt][nt][i] + bias;
                    const float ge = 0.5f * v * (1.f + erff(v * 0.7071067811865475f));
                    hid[(size_t)(hbase + rl) * HH + n] = f2bfu(ge);
                }
            }
    }
}

// Kernel 5: up, SINGLE pass over all 16 groups:
//   slots[tok*2+slot][n] = (hid @ WuT^T + bu) * gate   (bf16, write-only)
// Every slot row is written exactly once -> no atomics, no RMW, no ordering.
// grid: bx = ((g*MAXMT + tm)*8 + n0q), n0 = n0q*128
__global__ __launch_bounds__(256) void up_k(
    const ushort* __restrict__ hid, const ushort* __restrict__ WuT, const float* __restrict__ bu,
    const int* __restrict__ cnt, const unsigned* __restrict__ entries, ushort* __restrict__ slots)
{
    const int bx = blockIdx.x;
    const int n0 = (bx & 7) * 128;
    const int tmg = bx >> 3;
    const int tm = tmg % MAXMT;
    const int g = tmg / MAXMT, e = g >> 1, slot = g & 1;
    const int n_g = cnt[g * 16];
    if (tm * 128 >= n_g) return;

    int hbase = 0;
    for (int gg = 0; gg < g; ++gg) hbase += cnt[gg * 16];  // exclusive prefix

    __shared__ __align__(16) ushort As[128 * 64];
    __shared__ __align__(16) ushort Bs[128 * 64];
    __shared__ unsigned ecache[128];

    const int tid = threadIdx.x, lane = tid & 63, w = tid >> 6;
    const int wm = w >> 1, wn = w & 1;
    const int fr = lane & 15, fq = lane >> 4;

    if (tid < 128) {
        const int ridx = min(tm * 128 + tid, n_g - 1);
        ecache[tid] = entries[g * NTOK + ridx];
    }
    __syncthreads();

    const int lr = lane >> 3, seg = lane & 7;
    const int slog = seg ^ lr;
    const ushort* gA[4]; const ushort* gB[4];
    char* lA[4]; char* lB[4];
    const ushort* WTe = WuT + (size_t)e * DD * HH;
#pragma unroll
    for (int j = 0; j < 4; ++j) {
        const int row = w * 32 + j * 8 + lr;
        const int ar = min(tm * 128 + row, n_g - 1);
        gA[j] = hid + (size_t)(hbase + ar) * HH + slog * 8;
        gB[j] = WTe + (size_t)(n0 + row) * HH + slog * 8;
        lA[j] = (char*)As + (size_t)(w * 256 + j * 64) * 16;
        lB[j] = (char*)Bs + (size_t)(w * 256 + j * 64) * 16;
    }

    floatx4 acc[4][4];
#pragma unroll
    for (int i = 0; i < 4; ++i)
#pragma unroll
        for (int j = 0; j < 4; ++j) acc[i][j] = (floatx4){0.f, 0.f, 0.f, 0.f};

    const int axr = wm * 64 + fr;
    const int bxr = wn * 64 + fr;

    for (int k0 = 0; k0 < HH; k0 += 64) {
        __syncthreads();
#pragma unroll
        for (int j = 0; j < 4; ++j) { glds16(gA[j] + k0, lA[j]); glds16(gB[j] + k0, lB[j]); }
        __syncthreads();
#pragma unroll
        for (int kh = 0; kh < 2; ++kh) {
            short8 a[4], b[4];
#pragma unroll
            for (int mt = 0; mt < 4; ++mt) {
                const int r = axr + mt * 16;
                a[mt] = *(const short8*)&As[r * 64 + ((kh * 4 + fq) ^ (r & 7)) * 8];
            }
#pragma unroll
            for (int nt = 0; nt < 4; ++nt) {
                const int r = bxr + nt * 16;
                b[nt] = *(const short8*)&Bs[r * 64 + ((kh * 4 + fq) ^ (r & 7)) * 8];
            }
#pragma unroll
            for (int mt = 0; mt < 4; ++mt)
#pragma unroll
                for (int nt = 0; nt < 4; ++nt)
                    acc[mt][nt] = __builtin_amdgcn_mfma_f32_16x16x32_bf16(a[mt], b[nt], acc[mt][nt], 0, 0, 0);
        }
    }

#pragma unroll
    for (int nt = 0; nt < 4; ++nt) {
        const int n = n0 + wn * 64 + nt * 16 + fr;
        const float bias = bu[e * DD + n];
#pragma unroll
        for (int mt = 0; mt < 4; ++mt)
#pragma unroll
            for (int i = 0; i < 4; ++i) {
                const int rl = wm * 64 + mt * 16 + fq * 4 + i;
                if (tm * 128 + rl < n_g) {
                    const unsigned en = ecache[rl];
                    const int tok = (int)(en & 0xFFFFu);
                    ushort hb = (ushort)(en >> 16);
                    const float gate = __half2float(*reinterpret_cast<__half*>(&hb));
                    const float v = (acc[mt][nt][i] + bias) * gate;
                    slots[((size_t)tok * 2 + slot) * DD + n] = f2bfu(v);
                }
            }
    }
}

// Kernel 6: out[t][d] = slots[2t][d] + slots[2t+1][d]  (fp32 out, 8 elems/thread)
__global__ __launch_bounds__(256) void combine_k(
    const ushort* __restrict__ slots, float* __restrict__ out)
{
    const size_t flat = ((size_t)blockIdx.x * 256 + threadIdx.x) * 8;
    const size_t t = flat >> 10;         // / DD
    const size_t d = flat & (DD - 1);
    union { uint4 v; ushort h[8]; } a, b;
    a.v = *(const uint4*)(slots + ((t * 2 + 0) << 10) + d);
    b.v = *(const uint4*)(slots + ((t * 2 + 1) << 10) + d);
    float o[8];
#pragma unroll
    for (int j = 0; j < 8; ++j) o[j] = bfu2f(a.h[j]) + bfu2f(b.h[j]);
    *(float4*)(out + flat) = *(const float4*)&o[0];
    *(float4*)(out + flat + 4) = *(const float4*)&o[4];
}

// ---------------------------------------------------------------------------
// Workspace layout (bytes), total ~145 MB:
//   0         cnt    : int[16] @ 64B stride (256-int region zeroed by trans_k)
//   1024      (unused; old off slot)
//   2048      entries: u32[16][16384]            (1 MB)
//   1050624   xb     : bf16 [16384][1024]        (32 MB)
//   34605056  WdT    : bf16 [8][512 h][1024 d]   (8 MB)
//   42993664  WuT    : bf16 [8][1024 d][512 h]   (8 MB)
//   51382272  hid    : bf16 [32768][512]         (32 MB)
//   84936704  slots  : bf16 [32768][1024]        (64 MB)
// ---------------------------------------------------------------------------
extern "C" void kernel_launch(void* const* d_in, const int* in_sizes, int n_in,
                              void* d_out, int out_size, void* d_ws, size_t ws_size,
                              hipStream_t stream)
{
    const float* x     = (const float*)d_in[0];
    const float* Wr    = (const float*)d_in[1];
    const float* br    = (const float*)d_in[2];
    const float* Wn    = (const float*)d_in[3];
    const float* bn    = (const float*)d_in[4];
    const float* Wd    = (const float*)d_in[5];
    const float* bd    = (const float*)d_in[6];
    const float* Wu    = (const float*)d_in[7];
    const float* bu    = (const float*)d_in[8];
    const float* noise = (const float*)d_in[9];

    char* ws = (char*)d_ws;
    int*      cnt     = (int*)(ws + 0);
    unsigned* entries = (unsigned*)(ws + 2048);
    ushort*   xb      = (ushort*)(ws + 1050624);
    ushort*   WdT     = (ushort*)(ws + 34605056);
    ushort*   WuT     = (ushort*)(ws + 42993664);
    ushort*   hid     = (ushort*)(ws + 51382272);
    ushort*   slots   = (ushort*)(ws + 84936704);

    trans_k<<<dim3(HH / 64, DD / 64, EE), 256, 0, stream>>>(Wd, WdT, DD, HH, cnt);      // [d][h]->[h][d] + zero cnt
    trans_k<<<dim3(DD / 64, HH / 64, EE), 256, 0, stream>>>(Wu, WuT, HH, DD, nullptr);  // [h][d]->[d][h]
    router_k<<<NTOK / 16, 512, 0, stream>>>(x, Wr, br, Wn, bn, noise, cnt, entries, xb);
    down_k<<<NG * MAXMT * 4, 256, 0, stream>>>(xb, WdT, bd, cnt, entries, hid);
    up_k<<<NG * MAXMT * 8, 256, 0, stream>>>(hid, WuT, bu, cnt, entries, slots);
    combine_k<<<(NTOK * DD) / (256 * 8), 256, 0, stream>>>(slots, (float*)d_out);
}